// Round 1
// baseline (434.718 us; speedup 1.0000x reference)
//
#include <hip/hip_runtime.h>
#include <hip/hip_fp16.h>
#include <math.h>

#define NB 32
#define NN 512
#define DD 256
#define NROW  (NB*NN)      // 16384 rows per input
#define NELEM (NB*NN*DD)   // 4194304 elements per input

constexpr float INV_EPS   = 10.0f;
constexpr float F_TINY    = 1e-16f;
constexpr float F_NORMEPS = 1e-8f;
constexpr float MARG      = 1.0f / 512.0f;   // a = b = 1/n

typedef __attribute__((ext_vector_type(8))) short bf16x8;
typedef __attribute__((ext_vector_type(4))) float f32x4;

__device__ __forceinline__ unsigned short f2bf(float f) {
    unsigned u = __float_as_uint(f);
    u += 0x7fffu + ((u >> 16) & 1u);          // round-to-nearest-even
    return (unsigned short)(u >> 16);
}

// ---------------------------------------------------------------------------
// Fused: row norms of x,y + bf16 convert + zero cost + zero barrier counters.
// One wave per row (256 floats, float4/lane). 8192 blocks x 256.
// ---------------------------------------------------------------------------
__global__ __launch_bounds__(256) void norms_convert(
        const float* __restrict__ x, const float* __restrict__ y,
        float* __restrict__ nx, float* __restrict__ ny,
        unsigned short* __restrict__ xh, unsigned short* __restrict__ yh,
        float* __restrict__ cost, int* __restrict__ bars) {
    if (blockIdx.x == 0 && threadIdx.x < NB) cost[threadIdx.x] = 0.0f;
    if (blockIdx.x == 0 && threadIdx.x < 33) bars[threadIdx.x] = 0;
    int w = threadIdx.x >> 6, l = threadIdx.x & 63;
    int row = blockIdx.x * 4 + w;             // 0..32767
    bool isx = row < NROW;
    int r = isx ? row : row - NROW;
    const float* src = (isx ? x : y) + (size_t)r * DD;
    float4 v = ((const float4*)src)[l];
    float ss = v.x * v.x + v.y * v.y + v.z * v.z + v.w * v.w;
#pragma unroll
    for (int off = 32; off; off >>= 1) ss += __shfl_xor(ss, off);

    unsigned short* ph = (isx ? xh : yh) + (size_t)r * DD + l * 4;
    *(ushort4*)ph = make_ushort4(f2bf(v.x), f2bf(v.y), f2bf(v.z), f2bf(v.w));
    if (l == 0) (isx ? nx : ny)[r] = sqrtf(ss);
}

// ---------------------------------------------------------------------------
// C[b,n,m] = 1 - <x_n,y_m>/max(|x_n||y_m|, 1e-8), single bf16 MFMA.
// Fused epilogue also writes E = fp16(exp(-C/eps)).
// 128x128 tile, BK=32, 256 thr. XOR-swizzled LDS (verified in R4).
// ---------------------------------------------------------------------------
__global__ __launch_bounds__(256) void gemm_cos_mfma(
        const unsigned short* __restrict__ xh, const unsigned short* __restrict__ yh,
        const float* __restrict__ nx, const float* __restrict__ ny,
        float* __restrict__ C, __half* __restrict__ Ef) {
    int blk = blockIdx.x;
    int b = blk >> 4, ti = (blk >> 2) & 3, tj = blk & 3;
    __shared__ short Ah[128][32], Bh[128][32];
    const unsigned short* xbh = xh + ((size_t)b * NN + ti * 128) * DD;
    const unsigned short* ybh = yh + ((size_t)b * NN + tj * 128) * DD;
    int t = threadIdx.x, w = t >> 6, l = t & 63;
    int rw = w * 32, q = l >> 4, low = l & 15;

    f32x4 acc[2][8];
#pragma unroll
    for (int i = 0; i < 2; ++i)
#pragma unroll
        for (int j = 0; j < 8; ++j) acc[i][j] = (f32x4){0.f, 0.f, 0.f, 0.f};

    int sr = t >> 1, h = t & 1;               // staging: 2 threads/row
    int c0i = 2 * h, c1i = 2 * h + 1;         // logical 16B chunks
    int sw0 = (c0i ^ ((sr >> 1) & 3)) * 8;    // swizzled short offsets
    int sw1 = (c1i ^ ((sr >> 1) & 3)) * 8;

    for (int k0 = 0; k0 < DD; k0 += 32) {
        {
            const int4* ga = (const int4*)(xbh + (size_t)sr * DD + k0);
            const int4* gc = (const int4*)(ybh + (size_t)sr * DD + k0);
            int4 a0 = ga[c0i], a1 = ga[c1i];
            int4 c0 = gc[c0i], c1 = gc[c1i];
            *(int4*)&Ah[sr][sw0] = a0; *(int4*)&Ah[sr][sw1] = a1;
            *(int4*)&Bh[sr][sw0] = c0; *(int4*)&Bh[sr][sw1] = c1;
        }
        __syncthreads();

        bf16x8 ah[2];
#pragma unroll
        for (int ti2 = 0; ti2 < 2; ++ti2) {
            int m = rw + ti2 * 16 + low;
            int pq = (q ^ ((m >> 1) & 3)) * 8;
            ah[ti2] = *(const bf16x8*)&Ah[m][pq];
        }
#pragma unroll
        for (int tj2 = 0; tj2 < 8; ++tj2) {
            int n = tj2 * 16 + low;
            int pq = (q ^ ((n >> 1) & 3)) * 8;
            bf16x8 bh = *(const bf16x8*)&Bh[n][pq];
#pragma unroll
            for (int ti2 = 0; ti2 < 2; ++ti2)
                acc[ti2][tj2] = __builtin_amdgcn_mfma_f32_16x16x32_bf16(
                    ah[ti2], bh, acc[ti2][tj2], 0, 0, 0);
        }
        __syncthreads();
    }

    // epilogue: C/D layout col=lane&15, row=(lane>>4)*4+reg  [m89-corrected]
    float*  Cb = C  + (size_t)b * NN * NN;
    __half* Eb = Ef + (size_t)b * NN * NN;
#pragma unroll
    for (int ti2 = 0; ti2 < 2; ++ti2) {
#pragma unroll
        for (int tj2 = 0; tj2 < 8; ++tj2) {
            int gm0 = ti * 128 + rw + ti2 * 16 + q * 4;
            int gn  = tj * 128 + tj2 * 16 + low;
            float nyc = ny[b * NN + gn];
            f32x4 a = acc[ti2][tj2];
#pragma unroll
            for (int reg = 0; reg < 4; ++reg) {
                int gm = gm0 + reg;
                float d = 1.0f - a[reg] / fmaxf(nx[b * NN + gm] * nyc, F_NORMEPS);
                Cb[(size_t)gm * NN + gn] = d;
                Eb[(size_t)gm * NN + gn] = __float2half(__expf(-INV_EPS * d));
            }
        }
    }
}

// ---------------------------------------------------------------------------
// Fully fused Sinkhorn: 15 iterations + finish_q + pi_cost in ONE cooperative
// launch. 256 blocks x 512 thr, 1 block/CU, all co-resident.
// Block = 64-row stripe of one batch; E stripe lives in registers (64/thread)
// across all iterations; A (row scaling), B (col scaling), P are registers.
// Only the per-stripe column partials (cp) cross blocks; synchronized by a
// per-batch 8-block arrive/spin barrier (device-scope atomics + threadfence).
// One grid-wide barrier before the pi phase (cp scratch aliases pi rows).
// ---------------------------------------------------------------------------
__global__ __launch_bounds__(512, 2) void sink_fused(
        const __half* __restrict__ Ef, const float* __restrict__ C,
        float* __restrict__ cp0, float* __restrict__ cp1,
        float* __restrict__ pi, float* __restrict__ cost,
        int* __restrict__ bars) {
    int blk = blockIdx.x;
    int xcd = blk & 7, qq = blk >> 3;
    int o = qq & 7;                       // stripe slot within batch
    int b = ((qq >> 3) << 3) | xcd;       // batch (8 stripes share blk%8/XCD)
    int blkbase = blk - 8 * o;            // slot-0 block id of this batch
    int tt = threadIdx.x, w = tt >> 6, l = tt & 63;
    int r0 = o * 64 + w * 8;              // wave's first row

    __shared__ float sW[NN];              // w_m (later reused for Q)
    __shared__ float sWP[8][NN];          // per-wave column partials
    __shared__ float sPart[8];

    // ---- load E stripe into registers ONCE: lane owns cols 8l..8l+7
    float E[8][8];
    const __half* Eb = Ef + ((size_t)b * NN + r0) * NN + 8 * l;
#pragma unroll
    for (int i = 0; i < 8; ++i) {
        int4 raw = *(const int4*)(Eb + (size_t)i * NN);
        const __half* hv = (const __half*)&raw;
#pragma unroll
        for (int e = 0; e < 8; ++e) E[i][e] = __half2float(hv[e]);
    }

    float A[8], Pr[8];
#pragma unroll
    for (int i = 0; i < 8; ++i) { A[i] = 1.0f; Pr[i] = 0.0f; }
    float Br = 1.0f;                      // cumulative col scaling (redundant/block)

    float* cpr = cp0;                     // read buffer (after swap discipline)
    float* cpw = cp1;                     // iter 1 writes cp1

    for (int t = 1; t <= 15; ++t) {
        // ---- step 1: finish v_{t-1}; t==1 has v_0=1, B_0=1
        if (t == 1) {
            sW[tt] = 1.0f;
        } else {
            float sv = 0.0f;
#pragma unroll
            for (int k = 0; k < 8; ++k)
                sv += cpr[(size_t)(blkbase + 8 * k) * NN + tt];
            float vv = MARG / (Br * sv + F_TINY);
            Br *= vv;                      // B_{t-1}
            sW[tt] = Br * vv;              // w_m
        }
        __syncthreads();

        // ---- step 2: u for own 8 rows
        float wr[8];
        *(float4*)&wr[0] = *(const float4*)&sW[8 * l];
        *(float4*)&wr[4] = *(const float4*)&sW[8 * l + 4];
#pragma unroll
        for (int i = 0; i < 8; ++i) {
            float s = 0.0f;
#pragma unroll
            for (int e = 0; e < 8; ++e) s = fmaf(E[i][e], wr[e], s);
#pragma unroll
            for (int off = 32; off; off >>= 1) s += __shfl_xor(s, off);
            float uu = MARG / (A[i] * s + F_TINY);
            A[i] *= uu;
            if (t == 15) Pr[i] = A[i] * uu;   // P = A_15 * u_15 (all lanes)
        }

        // ---- step 3: column partials over own stripe with A_t
        float p[8];
#pragma unroll
        for (int e = 0; e < 8; ++e) {
            float s = 0.0f;
#pragma unroll
            for (int i = 0; i < 8; ++i) s = fmaf(E[i][e], A[i], s);
            p[e] = s;
        }
        *(float4*)&sWP[w][8 * l]     = make_float4(p[0], p[1], p[2], p[3]);
        *(float4*)&sWP[w][8 * l + 4] = make_float4(p[4], p[5], p[6], p[7]);
        __syncthreads();
        float cs = 0.0f;
#pragma unroll
        for (int ww = 0; ww < 8; ++ww) cs += sWP[ww][tt];
        cpw[(size_t)blk * NN + tt] = cs;

        // ---- per-batch barrier: all 8 stripe blocks finished iter t
        __syncthreads();                  // drains vmcnt -> cp writes in L2
        if (tt == 0) {
            __threadfence();              // device-scope release (L2 wb)
            __hip_atomic_fetch_add(&bars[b], 1, __ATOMIC_RELAXED,
                                   __HIP_MEMORY_SCOPE_AGENT);
            while (__hip_atomic_load(&bars[b], __ATOMIC_RELAXED,
                                     __HIP_MEMORY_SCOPE_AGENT) < 8 * t)
                __builtin_amdgcn_s_sleep(1);
            __threadfence();              // device-scope acquire (L1/L2 inv)
        }
        __syncthreads();

        float* tmp = cpr; cpr = cpw; cpw = tmp;   // swap buffers
    }

    // ---- finish Q: each block computes full Q vector (redundant, cheap)
    {
        float sv = 0.0f;
#pragma unroll
        for (int k = 0; k < 8; ++k)
            sv += cpr[(size_t)(blkbase + 8 * k) * NN + tt];   // cp_15
        float vv = MARG / (Br * sv + F_TINY);                 // Br = B_14
        sW[tt] = Br * vv * vv;            // Q_m = B_15 * v_15 (reuse sW)
    }

    // ---- grid barrier: cp scratch aliases pi[batch 0] rows; all cp reads
    //      must complete before ANY block writes pi.
    __syncthreads();
    if (tt == 0) {
        __threadfence();
        __hip_atomic_fetch_add(&bars[32], 1, __ATOMIC_RELAXED,
                               __HIP_MEMORY_SCOPE_AGENT);
        while (__hip_atomic_load(&bars[32], __ATOMIC_RELAXED,
                                 __HIP_MEMORY_SCOPE_AGENT) < 256)
            __builtin_amdgcn_s_sleep(1);
        __threadfence();
    }
    __syncthreads();

    // ---- pi phase: identical math to old pi_cost (reads f32 C, __expf)
    float q0[8];
    *(float4*)&q0[0] = *(const float4*)&sW[4 * l];
    *(float4*)&q0[4] = *(const float4*)&sW[256 + 4 * l];
    const float* Cb = C + (size_t)b * NN * NN;
    float* pib = pi + (size_t)b * NN * NN;
    float csum = 0.0f;
#pragma unroll 1
    for (int i = 0; i < 8; ++i) {
        int r = o * 64 + w * 8 + i;
        float pf = Pr[i];
        const float* crow = Cb + (size_t)r * NN;
        float* prow = pib + (size_t)r * NN;
        float4 c0 = *(const float4*)(crow + 4 * l);
        float4 c1 = *(const float4*)(crow + 256 + 4 * l);
        float pv0 = pf * q0[0] * __expf(-INV_EPS * c0.x);
        float pv1 = pf * q0[1] * __expf(-INV_EPS * c0.y);
        float pv2 = pf * q0[2] * __expf(-INV_EPS * c0.z);
        float pv3 = pf * q0[3] * __expf(-INV_EPS * c0.w);
        float pv4 = pf * q0[4] * __expf(-INV_EPS * c1.x);
        float pv5 = pf * q0[5] * __expf(-INV_EPS * c1.y);
        float pv6 = pf * q0[6] * __expf(-INV_EPS * c1.z);
        float pv7 = pf * q0[7] * __expf(-INV_EPS * c1.w);
        *(float4*)(prow + 4 * l)       = make_float4(pv0, pv1, pv2, pv3);
        *(float4*)(prow + 256 + 4 * l) = make_float4(pv4, pv5, pv6, pv7);
        csum = fmaf(pv0, c0.x, csum); csum = fmaf(pv1, c0.y, csum);
        csum = fmaf(pv2, c0.z, csum); csum = fmaf(pv3, c0.w, csum);
        csum = fmaf(pv4, c1.x, csum); csum = fmaf(pv5, c1.y, csum);
        csum = fmaf(pv6, c1.z, csum); csum = fmaf(pv7, c1.w, csum);
    }
#pragma unroll
    for (int off = 32; off; off >>= 1) csum += __shfl_xor(csum, off);
    if (l == 0) sPart[w] = csum;
    __syncthreads();
    if (tt == 0) {
        float tot = 0.0f;
#pragma unroll
        for (int ww = 0; ww < 8; ++ww) tot += sPart[ww];
        atomicAdd(&cost[b], tot);
    }
}

// ---------------------------------------------------------------------------
extern "C" void kernel_launch(void* const* d_in, const int* in_sizes, int n_in,
                              void* d_out, int out_size, void* d_ws, size_t ws_size,
                              hipStream_t stream) {
    const float* x = (const float*)d_in[0];
    const float* y = (const float*)d_in[1];
    float* out  = (float*)d_out;
    float* cost = out;                                   // [32]
    float* pi   = out + 32;                              // [32*512*512]
    float* C    = out + 32 + (size_t)NB * NN * NN;       // [32*512*512]

    float* ws = (float*)d_ws;
    float* nx = ws;                    // 16384
    float* ny = ws + 16384;            // 16384
    int* bars = (int*)(ws + 32768);    // 33 ints: 32 per-batch + 1 global

    // pi region reuse (33.55 MB):
    //   [xh: 8.4 MB][yh: 8.4 MB][Ef16: 16.8 MB]
    // xh/yh dead after gemm; cp double-buffer (1 MB) lives in xh region.
    // pi itself rewritten only at the very end (after the grid barrier).
    unsigned short* xh = (unsigned short*)pi;
    unsigned short* yh = xh + NELEM;
    __half* Ef = (__half*)(yh + NELEM);
    float* cp0 = pi;
    float* cp1 = pi + 256 * NN;

    norms_convert<<<dim3(8192), dim3(256), 0, stream>>>(
        x, y, nx, ny, xh, yh, cost, bars);
    gemm_cos_mfma<<<dim3(512), dim3(256), 0, stream>>>(
        xh, yh, nx, ny, C, Ef);

    const __half* Ef_p = Ef; const float* C_p = C;
    float* cp0_p = cp0; float* cp1_p = cp1;
    float* pi_p = pi; float* cost_p = cost; int* bars_p = bars;
    void* args[] = { &Ef_p, &C_p, &cp0_p, &cp1_p, &pi_p, &cost_p, &bars_p };
    hipLaunchCooperativeKernel(reinterpret_cast<void*>(sink_fused),
                               dim3(256), dim3(512), args, 0, stream);
}

// Round 2
// 219.790 us; speedup vs baseline: 1.9779x; 1.9779x over previous
//
#include <hip/hip_runtime.h>
#include <hip/hip_fp16.h>
#include <math.h>

#define NB 32
#define NN 512
#define DD 256
#define NROW  (NB*NN)      // 16384 rows per input
#define NELEM (NB*NN*DD)   // 4194304 elements per input

constexpr float INV_EPS   = 10.0f;
constexpr float F_TINY    = 1e-16f;
constexpr float F_NORMEPS = 1e-8f;
constexpr float MARG      = 1.0f / 512.0f;   // a = b = 1/n

typedef __attribute__((ext_vector_type(8))) short bf16x8;
typedef __attribute__((ext_vector_type(4))) float f32x4;

__device__ __forceinline__ unsigned short f2bf(float f) {
    unsigned u = __float_as_uint(f);
    u += 0x7fffu + ((u >> 16) & 1u);          // round-to-nearest-even
    return (unsigned short)(u >> 16);
}

// ---------------------------------------------------------------------------
// Fused: row norms of x,y + bf16 convert + zero cost + zero barrier counters.
// One wave per row (256 floats, float4/lane). 8192 blocks x 256.
// ---------------------------------------------------------------------------
__global__ __launch_bounds__(256) void norms_convert(
        const float* __restrict__ x, const float* __restrict__ y,
        float* __restrict__ nx, float* __restrict__ ny,
        unsigned short* __restrict__ xh, unsigned short* __restrict__ yh,
        float* __restrict__ cost, int* __restrict__ bars) {
    if (blockIdx.x == 0 && threadIdx.x < NB) cost[threadIdx.x] = 0.0f;
    if (blockIdx.x == 0 && threadIdx.x < 33) bars[threadIdx.x] = 0;
    int w = threadIdx.x >> 6, l = threadIdx.x & 63;
    int row = blockIdx.x * 4 + w;             // 0..32767
    bool isx = row < NROW;
    int r = isx ? row : row - NROW;
    const float* src = (isx ? x : y) + (size_t)r * DD;
    float4 v = ((const float4*)src)[l];
    float ss = v.x * v.x + v.y * v.y + v.z * v.z + v.w * v.w;
#pragma unroll
    for (int off = 32; off; off >>= 1) ss += __shfl_xor(ss, off);

    unsigned short* ph = (isx ? xh : yh) + (size_t)r * DD + l * 4;
    *(ushort4*)ph = make_ushort4(f2bf(v.x), f2bf(v.y), f2bf(v.z), f2bf(v.w));
    if (l == 0) (isx ? nx : ny)[r] = sqrtf(ss);
}

// ---------------------------------------------------------------------------
// C[b,n,m] = 1 - <x_n,y_m>/max(|x_n||y_m|, 1e-8), single bf16 MFMA.
// Fused epilogue also writes E = fp16(exp(-C/eps)).
// 128x128 tile, BK=32, 256 thr. XOR-swizzled LDS (verified in R4).
// ---------------------------------------------------------------------------
__global__ __launch_bounds__(256) void gemm_cos_mfma(
        const unsigned short* __restrict__ xh, const unsigned short* __restrict__ yh,
        const float* __restrict__ nx, const float* __restrict__ ny,
        float* __restrict__ C, __half* __restrict__ Ef) {
    int blk = blockIdx.x;
    int b = blk >> 4, ti = (blk >> 2) & 3, tj = blk & 3;
    __shared__ short Ah[128][32], Bh[128][32];
    const unsigned short* xbh = xh + ((size_t)b * NN + ti * 128) * DD;
    const unsigned short* ybh = yh + ((size_t)b * NN + tj * 128) * DD;
    int t = threadIdx.x, w = t >> 6, l = t & 63;
    int rw = w * 32, q = l >> 4, low = l & 15;

    f32x4 acc[2][8];
#pragma unroll
    for (int i = 0; i < 2; ++i)
#pragma unroll
        for (int j = 0; j < 8; ++j) acc[i][j] = (f32x4){0.f, 0.f, 0.f, 0.f};

    int sr = t >> 1, h = t & 1;               // staging: 2 threads/row
    int c0i = 2 * h, c1i = 2 * h + 1;         // logical 16B chunks
    int sw0 = (c0i ^ ((sr >> 1) & 3)) * 8;    // swizzled short offsets
    int sw1 = (c1i ^ ((sr >> 1) & 3)) * 8;

    for (int k0 = 0; k0 < DD; k0 += 32) {
        {
            const int4* ga = (const int4*)(xbh + (size_t)sr * DD + k0);
            const int4* gc = (const int4*)(ybh + (size_t)sr * DD + k0);
            int4 a0 = ga[c0i], a1 = ga[c1i];
            int4 c0 = gc[c0i], c1 = gc[c1i];
            *(int4*)&Ah[sr][sw0] = a0; *(int4*)&Ah[sr][sw1] = a1;
            *(int4*)&Bh[sr][sw0] = c0; *(int4*)&Bh[sr][sw1] = c1;
        }
        __syncthreads();

        bf16x8 ah[2];
#pragma unroll
        for (int ti2 = 0; ti2 < 2; ++ti2) {
            int m = rw + ti2 * 16 + low;
            int pq = (q ^ ((m >> 1) & 3)) * 8;
            ah[ti2] = *(const bf16x8*)&Ah[m][pq];
        }
#pragma unroll
        for (int tj2 = 0; tj2 < 8; ++tj2) {
            int n = tj2 * 16 + low;
            int pq = (q ^ ((n >> 1) & 3)) * 8;
            bf16x8 bh = *(const bf16x8*)&Bh[n][pq];
#pragma unroll
            for (int ti2 = 0; ti2 < 2; ++ti2)
                acc[ti2][tj2] = __builtin_amdgcn_mfma_f32_16x16x32_bf16(
                    ah[ti2], bh, acc[ti2][tj2], 0, 0, 0);
        }
        __syncthreads();
    }

    // epilogue: C/D layout col=lane&15, row=(lane>>4)*4+reg  [m89-corrected]
    float*  Cb = C  + (size_t)b * NN * NN;
    __half* Eb = Ef + (size_t)b * NN * NN;
#pragma unroll
    for (int ti2 = 0; ti2 < 2; ++ti2) {
#pragma unroll
        for (int tj2 = 0; tj2 < 8; ++tj2) {
            int gm0 = ti * 128 + rw + ti2 * 16 + q * 4;
            int gn  = tj * 128 + tj2 * 16 + low;
            float nyc = ny[b * NN + gn];
            f32x4 a = acc[ti2][tj2];
#pragma unroll
            for (int reg = 0; reg < 4; ++reg) {
                int gm = gm0 + reg;
                float d = 1.0f - a[reg] / fmaxf(nx[b * NN + gm] * nyc, F_NORMEPS);
                Cb[(size_t)gm * NN + gn] = d;
                Eb[(size_t)gm * NN + gn] = __float2half(__expf(-INV_EPS * d));
            }
        }
    }
}

// ---------------------------------------------------------------------------
// Fully fused Sinkhorn: 15 iterations + finish_q + pi_cost in ONE cooperative
// launch. 256 blocks x 512 thr, 1 block/CU, all co-resident.
// Block = 64-row stripe of one batch.
// R1 fix: E stripe lives in LDS as fp16 (64 KB) — NOT registers (R0 spilled
// to scratch at VGPR_Count=64). Per iteration each thread ds_read_b128's its
// own 8x8 tile (lanes 16B apart -> conflict-free) and converts on the fly.
// R1 fix: no __threadfence. All 8 stripe blocks of a batch share blk&7 ->
// same XCD -> same (write-through) L2. cp reads use L1-bypassing agent-scope
// atomic loads (global_load_dword sc0). Grid barrier protects only the
// cp-aliases-pi anti-dependency; no data fence needed.
// ---------------------------------------------------------------------------
__global__ __launch_bounds__(512, 2) void sink_fused(
        const __half* __restrict__ Ef, const float* __restrict__ C,
        float* __restrict__ cp0, float* __restrict__ cp1,
        float* __restrict__ pi, float* __restrict__ cost,
        int* __restrict__ bars) {
    int blk = blockIdx.x;
    int xcd = blk & 7, qq = blk >> 3;
    int o = qq & 7;                       // stripe slot within batch
    int b = ((qq >> 3) << 3) | xcd;       // batch (8 stripes share blk%8/XCD)
    int blkbase = blk - 8 * o;            // slot-0 block id of this batch
    int tt = threadIdx.x, w = tt >> 6, l = tt & 63;

    __shared__ __half sE[64][NN];         // E stripe, fp16 (64 KB)
    __shared__ float sW[NN];              // w_m (later reused for Q)
    __shared__ float sWP[8][NN];          // per-wave column partials
    __shared__ float sPart[8];

    // ---- stage E stripe into LDS once: thread (w,l) owns rows w*8+i,
    //      cols 8l..8l+7 (one int4 per row)
    {
        const __half* Eb = Ef + ((size_t)b * NN + o * 64 + w * 8) * NN + 8 * l;
#pragma unroll
        for (int i = 0; i < 8; ++i) {
            int4 raw = *(const int4*)(Eb + (size_t)i * NN);
            *(int4*)&sE[w * 8 + i][8 * l] = raw;
        }
    }

    float A[8], Pr[8];
#pragma unroll
    for (int i = 0; i < 8; ++i) { A[i] = 1.0f; Pr[i] = 0.0f; }
    float Br = 1.0f;                      // cumulative col scaling (redundant/block)

    float* cpr = cp0;                     // read buffer
    float* cpw = cp1;                     // iter 1 writes cp1

    for (int t = 1; t <= 15; ++t) {
        // ---- step 1: finish v_{t-1}; t==1 has v_0=1, B_0=1
        if (t == 1) {
            sW[tt] = 1.0f;
        } else {
            float sv = 0.0f;
#pragma unroll
            for (int k = 0; k < 8; ++k)
                sv += __hip_atomic_load(
                    &cpr[(size_t)(blkbase + 8 * k) * NN + tt],
                    __ATOMIC_RELAXED, __HIP_MEMORY_SCOPE_AGENT);
            float vv = MARG / (Br * sv + F_TINY);
            Br *= vv;                      // B_{t-1}
            sW[tt] = Br * vv;              // w_m
        }
        __syncthreads();                  // sW ready (and sE on t==1)

        // ---- load own 8x8 E tile from LDS (raw fp16), used by steps 2+3
        int4 raw[8];
#pragma unroll
        for (int i = 0; i < 8; ++i)
            raw[i] = *(const int4*)&sE[w * 8 + i][8 * l];

        float wr[8];
        *(float4*)&wr[0] = *(const float4*)&sW[8 * l];
        *(float4*)&wr[4] = *(const float4*)&sW[8 * l + 4];

        // ---- step 2: u for own 8 rows
#pragma unroll
        for (int i = 0; i < 8; ++i) {
            const __half* hv = (const __half*)&raw[i];
            float s = 0.0f;
#pragma unroll
            for (int e = 0; e < 8; ++e) s = fmaf(__half2float(hv[e]), wr[e], s);
#pragma unroll
            for (int off = 32; off; off >>= 1) s += __shfl_xor(s, off);
            float uu = MARG / (A[i] * s + F_TINY);
            A[i] *= uu;
            if (t == 15) Pr[i] = A[i] * uu;   // P = A_15 * u_15 (all lanes)
        }

        // ---- step 3: column partials over own stripe with A_t
        float p[8];
#pragma unroll
        for (int e = 0; e < 8; ++e) p[e] = 0.0f;
#pragma unroll
        for (int i = 0; i < 8; ++i) {
            const __half* hv = (const __half*)&raw[i];
#pragma unroll
            for (int e = 0; e < 8; ++e)
                p[e] = fmaf(__half2float(hv[e]), A[i], p[e]);
        }
        *(float4*)&sWP[w][8 * l]     = make_float4(p[0], p[1], p[2], p[3]);
        *(float4*)&sWP[w][8 * l + 4] = make_float4(p[4], p[5], p[6], p[7]);
        __syncthreads();
        float cs = 0.0f;
#pragma unroll
        for (int ww = 0; ww < 8; ++ww) cs += sWP[ww][tt];
        cpw[(size_t)blk * NN + tt] = cs;

        // ---- per-batch barrier: all 8 stripe blocks (same XCD) done iter t.
        //      __syncthreads drains vmcnt -> cp stores are in L2 (L1 is
        //      write-through); readers use sc0 loads, so no fences needed.
        __syncthreads();
        if (tt == 0) {
            __hip_atomic_fetch_add(&bars[b], 1, __ATOMIC_RELAXED,
                                   __HIP_MEMORY_SCOPE_AGENT);
            while (__hip_atomic_load(&bars[b], __ATOMIC_RELAXED,
                                     __HIP_MEMORY_SCOPE_AGENT) < 8 * t)
                __builtin_amdgcn_s_sleep(1);
        }
        __syncthreads();

        float* tmp = cpr; cpr = cpw; cpw = tmp;   // swap buffers
    }

    // ---- finish Q: each block computes full Q vector (redundant, cheap)
    {
        float sv = 0.0f;
#pragma unroll
        for (int k = 0; k < 8; ++k)
            sv += __hip_atomic_load(
                &cpr[(size_t)(blkbase + 8 * k) * NN + tt],   // cp_15
                __ATOMIC_RELAXED, __HIP_MEMORY_SCOPE_AGENT);
        float vv = MARG / (Br * sv + F_TINY);                 // Br = B_14
        sW[tt] = Br * vv * vv;            // Q_m = B_15 * v_15 (reuse sW)
    }

    // ---- grid barrier: cp scratch aliases pi[batch 0] rows; all cp reads
    //      must complete before ANY block writes pi. (Anti-dependency only.)
    __syncthreads();
    if (tt == 0) {
        __hip_atomic_fetch_add(&bars[32], 1, __ATOMIC_RELAXED,
                               __HIP_MEMORY_SCOPE_AGENT);
        while (__hip_atomic_load(&bars[32], __ATOMIC_RELAXED,
                                 __HIP_MEMORY_SCOPE_AGENT) < 256)
            __builtin_amdgcn_s_sleep(1);
    }
    __syncthreads();

    // ---- pi phase: identical math to old pi_cost (reads f32 C, __expf)
    float q0[8];
    *(float4*)&q0[0] = *(const float4*)&sW[4 * l];
    *(float4*)&q0[4] = *(const float4*)&sW[256 + 4 * l];
    const float* Cb = C + (size_t)b * NN * NN;
    float* pib = pi + (size_t)b * NN * NN;
    float csum = 0.0f;
#pragma unroll 1
    for (int i = 0; i < 8; ++i) {
        int r = o * 64 + w * 8 + i;
        float pf = Pr[i];
        const float* crow = Cb + (size_t)r * NN;
        float* prow = pib + (size_t)r * NN;
        float4 c0 = *(const float4*)(crow + 4 * l);
        float4 c1 = *(const float4*)(crow + 256 + 4 * l);
        float pv0 = pf * q0[0] * __expf(-INV_EPS * c0.x);
        float pv1 = pf * q0[1] * __expf(-INV_EPS * c0.y);
        float pv2 = pf * q0[2] * __expf(-INV_EPS * c0.z);
        float pv3 = pf * q0[3] * __expf(-INV_EPS * c0.w);
        float pv4 = pf * q0[4] * __expf(-INV_EPS * c1.x);
        float pv5 = pf * q0[5] * __expf(-INV_EPS * c1.y);
        float pv6 = pf * q0[6] * __expf(-INV_EPS * c1.z);
        float pv7 = pf * q0[7] * __expf(-INV_EPS * c1.w);
        *(float4*)(prow + 4 * l)       = make_float4(pv0, pv1, pv2, pv3);
        *(float4*)(prow + 256 + 4 * l) = make_float4(pv4, pv5, pv6, pv7);
        csum = fmaf(pv0, c0.x, csum); csum = fmaf(pv1, c0.y, csum);
        csum = fmaf(pv2, c0.z, csum); csum = fmaf(pv3, c0.w, csum);
        csum = fmaf(pv4, c1.x, csum); csum = fmaf(pv5, c1.y, csum);
        csum = fmaf(pv6, c1.z, csum); csum = fmaf(pv7, c1.w, csum);
    }
#pragma unroll
    for (int off = 32; off; off >>= 1) csum += __shfl_xor(csum, off);
    if (l == 0) sPart[w] = csum;
    __syncthreads();
    if (tt == 0) {
        float tot = 0.0f;
#pragma unroll
        for (int ww = 0; ww < 8; ++ww) tot += sPart[ww];
        atomicAdd(&cost[b], tot);
    }
}

// ---------------------------------------------------------------------------
extern "C" void kernel_launch(void* const* d_in, const int* in_sizes, int n_in,
                              void* d_out, int out_size, void* d_ws, size_t ws_size,
                              hipStream_t stream) {
    const float* x = (const float*)d_in[0];
    const float* y = (const float*)d_in[1];
    float* out  = (float*)d_out;
    float* cost = out;                                   // [32]
    float* pi   = out + 32;                              // [32*512*512]
    float* C    = out + 32 + (size_t)NB * NN * NN;       // [32*512*512]

    float* ws = (float*)d_ws;
    float* nx = ws;                    // 16384
    float* ny = ws + 16384;            // 16384
    int* bars = (int*)(ws + 32768);    // 33 ints: 32 per-batch + 1 global

    // pi region reuse (33.55 MB):
    //   [xh: 8.4 MB][yh: 8.4 MB][Ef16: 16.8 MB]
    // xh/yh dead after gemm; cp double-buffer (1 MB) lives in xh region.
    // pi itself rewritten only at the very end (after the grid barrier).
    unsigned short* xh = (unsigned short*)pi;
    unsigned short* yh = xh + NELEM;
    __half* Ef = (__half*)(yh + NELEM);
    float* cp0 = pi;
    float* cp1 = pi + 256 * NN;

    norms_convert<<<dim3(8192), dim3(256), 0, stream>>>(
        x, y, nx, ny, xh, yh, cost, bars);
    gemm_cos_mfma<<<dim3(512), dim3(256), 0, stream>>>(
        xh, yh, nx, ny, C, Ef);

    const __half* Ef_p = Ef; const float* C_p = C;
    float* cp0_p = cp0; float* cp1_p = cp1;
    float* pi_p = pi; float* cost_p = cost; int* bars_p = bars;
    void* args[] = { &Ef_p, &C_p, &cp0_p, &cp1_p, &pi_p, &cost_p, &bars_p };
    hipLaunchCooperativeKernel(reinterpret_cast<void*>(sink_fused),
                               dim3(256), dim3(512), args, 0, stream);
}

// Round 3
// 188.035 us; speedup vs baseline: 2.3119x; 1.1689x over previous
//
#include <hip/hip_runtime.h>
#include <hip/hip_fp16.h>
#include <math.h>

#define NB 32
#define NN 512
#define DD 256
#define NROW  (NB*NN)      // 16384 rows per input
#define NELEM (NB*NN*DD)   // 4194304 elements per input

constexpr float INV_EPS   = 10.0f;
constexpr float F_TINY    = 1e-16f;
constexpr float F_NORMEPS = 1e-8f;
constexpr float MARG      = 1.0f / 512.0f;   // a = b = 1/n

// bars layout (ints, 256B padding): per-batch counter at [b*64],
// per-batch release flag at [b*64+16], global tree counter at [2048].
#define BARS_N 2112

typedef __attribute__((ext_vector_type(8))) short bf16x8;
typedef __attribute__((ext_vector_type(4))) float f32x4;

__device__ __forceinline__ unsigned short f2bf(float f) {
    unsigned u = __float_as_uint(f);
    u += 0x7fffu + ((u >> 16) & 1u);          // round-to-nearest-even
    return (unsigned short)(u >> 16);
}

// ---------------------------------------------------------------------------
// Fused: row norms of x,y + bf16 convert + zero cost + zero barrier counters.
// One wave per row (256 floats, float4/lane). 8192 blocks x 256.
// ---------------------------------------------------------------------------
__global__ __launch_bounds__(256) void norms_convert(
        const float* __restrict__ x, const float* __restrict__ y,
        float* __restrict__ nx, float* __restrict__ ny,
        unsigned short* __restrict__ xh, unsigned short* __restrict__ yh,
        float* __restrict__ cost, int* __restrict__ bars) {
    if (blockIdx.x == 0) {
        if (threadIdx.x < NB) cost[threadIdx.x] = 0.0f;
        for (int i = threadIdx.x; i < BARS_N; i += 256) bars[i] = 0;
    }
    int w = threadIdx.x >> 6, l = threadIdx.x & 63;
    int row = blockIdx.x * 4 + w;             // 0..32767
    bool isx = row < NROW;
    int r = isx ? row : row - NROW;
    const float* src = (isx ? x : y) + (size_t)r * DD;
    float4 v = ((const float4*)src)[l];
    float ss = v.x * v.x + v.y * v.y + v.z * v.z + v.w * v.w;
#pragma unroll
    for (int off = 32; off; off >>= 1) ss += __shfl_xor(ss, off);

    unsigned short* ph = (isx ? xh : yh) + (size_t)r * DD + l * 4;
    *(ushort4*)ph = make_ushort4(f2bf(v.x), f2bf(v.y), f2bf(v.z), f2bf(v.w));
    if (l == 0) (isx ? nx : ny)[r] = sqrtf(ss);
}

// ---------------------------------------------------------------------------
// C[b,n,m] = 1 - <x_n,y_m>/max(|x_n||y_m|, 1e-8), single bf16 MFMA.
// Fused epilogue also writes E = fp16(exp(-C/eps)).
// 128x128 tile, BK=32, 256 thr. XOR-swizzled LDS.
// ---------------------------------------------------------------------------
__global__ __launch_bounds__(256) void gemm_cos_mfma(
        const unsigned short* __restrict__ xh, const unsigned short* __restrict__ yh,
        const float* __restrict__ nx, const float* __restrict__ ny,
        float* __restrict__ C, __half* __restrict__ Ef) {
    int blk = blockIdx.x;
    int b = blk >> 4, ti = (blk >> 2) & 3, tj = blk & 3;
    __shared__ short Ah[128][32], Bh[128][32];
    const unsigned short* xbh = xh + ((size_t)b * NN + ti * 128) * DD;
    const unsigned short* ybh = yh + ((size_t)b * NN + tj * 128) * DD;
    int t = threadIdx.x, w = t >> 6, l = t & 63;
    int rw = w * 32, q = l >> 4, low = l & 15;

    f32x4 acc[2][8];
#pragma unroll
    for (int i = 0; i < 2; ++i)
#pragma unroll
        for (int j = 0; j < 8; ++j) acc[i][j] = (f32x4){0.f, 0.f, 0.f, 0.f};

    int sr = t >> 1, h = t & 1;               // staging: 2 threads/row
    int c0i = 2 * h, c1i = 2 * h + 1;         // logical 16B chunks
    int sw0 = (c0i ^ ((sr >> 1) & 3)) * 8;    // swizzled short offsets
    int sw1 = (c1i ^ ((sr >> 1) & 3)) * 8;

    for (int k0 = 0; k0 < DD; k0 += 32) {
        {
            const int4* ga = (const int4*)(xbh + (size_t)sr * DD + k0);
            const int4* gc = (const int4*)(ybh + (size_t)sr * DD + k0);
            int4 a0 = ga[c0i], a1 = ga[c1i];
            int4 c0 = gc[c0i], c1 = gc[c1i];
            *(int4*)&Ah[sr][sw0] = a0; *(int4*)&Ah[sr][sw1] = a1;
            *(int4*)&Bh[sr][sw0] = c0; *(int4*)&Bh[sr][sw1] = c1;
        }
        __syncthreads();

        bf16x8 ah[2];
#pragma unroll
        for (int ti2 = 0; ti2 < 2; ++ti2) {
            int m = rw + ti2 * 16 + low;
            int pq = (q ^ ((m >> 1) & 3)) * 8;
            ah[ti2] = *(const bf16x8*)&Ah[m][pq];
        }
#pragma unroll
        for (int tj2 = 0; tj2 < 8; ++tj2) {
            int n = tj2 * 16 + low;
            int pq = (q ^ ((n >> 1) & 3)) * 8;
            bf16x8 bh = *(const bf16x8*)&Bh[n][pq];
#pragma unroll
            for (int ti2 = 0; ti2 < 2; ++ti2)
                acc[ti2][tj2] = __builtin_amdgcn_mfma_f32_16x16x32_bf16(
                    ah[ti2], bh, acc[ti2][tj2], 0, 0, 0);
        }
        __syncthreads();
    }

    // epilogue: C/D layout col=lane&15, row=(lane>>4)*4+reg  [m89-corrected]
    float*  Cb = C  + (size_t)b * NN * NN;
    __half* Eb = Ef + (size_t)b * NN * NN;
#pragma unroll
    for (int ti2 = 0; ti2 < 2; ++ti2) {
#pragma unroll
        for (int tj2 = 0; tj2 < 8; ++tj2) {
            int gm0 = ti * 128 + rw + ti2 * 16 + q * 4;
            int gn  = tj * 128 + tj2 * 16 + low;
            float nyc = ny[b * NN + gn];
            f32x4 a = acc[ti2][tj2];
#pragma unroll
            for (int reg = 0; reg < 4; ++reg) {
                int gm = gm0 + reg;
                float d = 1.0f - a[reg] / fmaxf(nx[b * NN + gm] * nyc, F_NORMEPS);
                Cb[(size_t)gm * NN + gn] = d;
                Eb[(size_t)gm * NN + gn] = __float2half(__expf(-INV_EPS * d));
            }
        }
    }
}

// ---------------------------------------------------------------------------
// Fully fused Sinkhorn: 15 iterations + finish_q + pi_cost in ONE cooperative
// launch. 256 blocks x 512 thr, 1 block/CU, all co-resident.
// Block = 64-row stripe of one batch; E stripe in LDS fp16 (64 KB).
// R3 fix: per-batch barrier counters PADDED to one 256B line each (R2 had all
// 32 counters in 2-3 lines -> 256 agent-scope pollers serializing on the
// lines' home L3 slot ~= the 5 us/iter stall). Grid barrier replaced by a
// 2-level tree (batch arrive -> 32 leaders on global counter -> per-batch
// padded release flag): max 32 pollers on any line, one-time.
// ---------------------------------------------------------------------------
__global__ __launch_bounds__(512, 2) void sink_fused(
        const __half* __restrict__ Ef, const float* __restrict__ C,
        float* __restrict__ cp0, float* __restrict__ cp1,
        float* __restrict__ pi, float* __restrict__ cost,
        int* __restrict__ bars) {
    int blk = blockIdx.x;
    int xcd = blk & 7, qq = blk >> 3;
    int o = qq & 7;                       // stripe slot within batch
    int b = ((qq >> 3) << 3) | xcd;       // batch (8 stripes share blk%8/XCD)
    int blkbase = blk - 8 * o;            // slot-0 block id of this batch
    int tt = threadIdx.x, w = tt >> 6, l = tt & 63;
    int* bcnt = &bars[b * 64];            // per-batch counter (own 256B line)
    int* brel = &bars[b * 64 + 16];       // per-batch release flag (same line)
    int* gcnt = &bars[2048];              // global tree counter

    __shared__ __half sE[64][NN];         // E stripe, fp16 (64 KB)
    __shared__ float sW[NN];              // w_m (later reused for Q)
    __shared__ float sWP[8][NN];          // per-wave column partials
    __shared__ float sPart[8];

    // ---- stage E stripe into LDS once: thread (w,l) owns rows w*8+i,
    //      cols 8l..8l+7 (one int4 per row)
    {
        const __half* Eb = Ef + ((size_t)b * NN + o * 64 + w * 8) * NN + 8 * l;
#pragma unroll
        for (int i = 0; i < 8; ++i) {
            int4 raw = *(const int4*)(Eb + (size_t)i * NN);
            *(int4*)&sE[w * 8 + i][8 * l] = raw;
        }
    }

    float A[8], Pr[8];
#pragma unroll
    for (int i = 0; i < 8; ++i) { A[i] = 1.0f; Pr[i] = 0.0f; }
    float Br = 1.0f;                      // cumulative col scaling (redundant/block)

    float* cpr = cp0;                     // read buffer
    float* cpw = cp1;                     // iter 1 writes cp1

    for (int t = 1; t <= 15; ++t) {
        // ---- step 1: finish v_{t-1}; t==1 has v_0=1, B_0=1
        if (t == 1) {
            sW[tt] = 1.0f;
        } else {
            float sv = 0.0f;
#pragma unroll
            for (int k = 0; k < 8; ++k)
                sv += __hip_atomic_load(
                    &cpr[(size_t)(blkbase + 8 * k) * NN + tt],
                    __ATOMIC_RELAXED, __HIP_MEMORY_SCOPE_AGENT);
            float vv = MARG / (Br * sv + F_TINY);
            Br *= vv;                      // B_{t-1}
            sW[tt] = Br * vv;              // w_m
        }
        __syncthreads();                  // sW ready (and sE on t==1)

        // ---- load own 8x8 E tile from LDS (raw fp16), used by steps 2+3
        int4 raw[8];
#pragma unroll
        for (int i = 0; i < 8; ++i)
            raw[i] = *(const int4*)&sE[w * 8 + i][8 * l];

        float wr[8];
        *(float4*)&wr[0] = *(const float4*)&sW[8 * l];
        *(float4*)&wr[4] = *(const float4*)&sW[8 * l + 4];

        // ---- step 2: u for own 8 rows
#pragma unroll
        for (int i = 0; i < 8; ++i) {
            const __half* hv = (const __half*)&raw[i];
            float s = 0.0f;
#pragma unroll
            for (int e = 0; e < 8; ++e) s = fmaf(__half2float(hv[e]), wr[e], s);
#pragma unroll
            for (int off = 32; off; off >>= 1) s += __shfl_xor(s, off);
            float uu = MARG / (A[i] * s + F_TINY);
            A[i] *= uu;
            if (t == 15) Pr[i] = A[i] * uu;   // P = A_15 * u_15 (all lanes)
        }

        // ---- step 3: column partials over own stripe with A_t
        float p[8];
#pragma unroll
        for (int e = 0; e < 8; ++e) p[e] = 0.0f;
#pragma unroll
        for (int i = 0; i < 8; ++i) {
            const __half* hv = (const __half*)&raw[i];
#pragma unroll
            for (int e = 0; e < 8; ++e)
                p[e] = fmaf(__half2float(hv[e]), A[i], p[e]);
        }
        *(float4*)&sWP[w][8 * l]     = make_float4(p[0], p[1], p[2], p[3]);
        *(float4*)&sWP[w][8 * l + 4] = make_float4(p[4], p[5], p[6], p[7]);
        __syncthreads();
        float cs = 0.0f;
#pragma unroll
        for (int ww = 0; ww < 8; ++ww) cs += sWP[ww][tt];
        cpw[(size_t)blk * NN + tt] = cs;

        // ---- per-batch barrier: all 8 stripe blocks (same XCD) done iter t.
        //      __syncthreads drains vmcnt -> cp stores are in L2 (L1 is
        //      write-through); readers use sc0 loads, so no fences needed.
        __syncthreads();
        if (tt == 0) {
            __hip_atomic_fetch_add(bcnt, 1, __ATOMIC_RELAXED,
                                   __HIP_MEMORY_SCOPE_AGENT);
            while (__hip_atomic_load(bcnt, __ATOMIC_RELAXED,
                                     __HIP_MEMORY_SCOPE_AGENT) < 8 * t)
                __builtin_amdgcn_s_sleep(1);
        }
        __syncthreads();

        float* tmp = cpr; cpr = cpw; cpw = tmp;   // swap buffers
    }

    // ---- finish Q: each block computes full Q vector (redundant, cheap)
    {
        float sv = 0.0f;
#pragma unroll
        for (int k = 0; k < 8; ++k)
            sv += __hip_atomic_load(
                &cpr[(size_t)(blkbase + 8 * k) * NN + tt],   // cp_15
                __ATOMIC_RELAXED, __HIP_MEMORY_SCOPE_AGENT);
        float vv = MARG / (Br * sv + F_TINY);                 // Br = B_14
        sW[tt] = Br * vv * vv;            // Q_m = B_15 * v_15 (reuse sW)
    }

    // ---- grid barrier (2-level tree): cp scratch aliases pi rows; all cp
    //      reads must finish before ANY block writes pi. (Anti-dep only.)
    __syncthreads();                      // all waves done reading cp
    if (tt == 0) {
        // level 1: per-batch arrive (counter reaches 120 + 8 = 128)
        __hip_atomic_fetch_add(bcnt, 1, __ATOMIC_RELAXED,
                               __HIP_MEMORY_SCOPE_AGENT);
        if (o == 0) {
            while (__hip_atomic_load(bcnt, __ATOMIC_RELAXED,
                                     __HIP_MEMORY_SCOPE_AGENT) < 128)
                __builtin_amdgcn_s_sleep(1);
            // level 2: 32 batch leaders on the global counter
            __hip_atomic_fetch_add(gcnt, 1, __ATOMIC_RELAXED,
                                   __HIP_MEMORY_SCOPE_AGENT);
            while (__hip_atomic_load(gcnt, __ATOMIC_RELAXED,
                                     __HIP_MEMORY_SCOPE_AGENT) < 32)
                __builtin_amdgcn_s_sleep(1);
            __hip_atomic_store(brel, 1, __ATOMIC_RELAXED,
                               __HIP_MEMORY_SCOPE_AGENT);
        } else {
            while (__hip_atomic_load(brel, __ATOMIC_RELAXED,
                                     __HIP_MEMORY_SCOPE_AGENT) == 0)
                __builtin_amdgcn_s_sleep(1);
        }
    }
    __syncthreads();

    // ---- pi phase: identical math to old pi_cost (reads f32 C, __expf)
    float q0[8];
    *(float4*)&q0[0] = *(const float4*)&sW[4 * l];
    *(float4*)&q0[4] = *(const float4*)&sW[256 + 4 * l];
    const float* Cb = C + (size_t)b * NN * NN;
    float* pib = pi + (size_t)b * NN * NN;
    float csum = 0.0f;
#pragma unroll 1
    for (int i = 0; i < 8; ++i) {
        int r = o * 64 + w * 8 + i;
        float pf = Pr[i];
        const float* crow = Cb + (size_t)r * NN;
        float* prow = pib + (size_t)r * NN;
        float4 c0 = *(const float4*)(crow + 4 * l);
        float4 c1 = *(const float4*)(crow + 256 + 4 * l);
        float pv0 = pf * q0[0] * __expf(-INV_EPS * c0.x);
        float pv1 = pf * q0[1] * __expf(-INV_EPS * c0.y);
        float pv2 = pf * q0[2] * __expf(-INV_EPS * c0.z);
        float pv3 = pf * q0[3] * __expf(-INV_EPS * c0.w);
        float pv4 = pf * q0[4] * __expf(-INV_EPS * c1.x);
        float pv5 = pf * q0[5] * __expf(-INV_EPS * c1.y);
        float pv6 = pf * q0[6] * __expf(-INV_EPS * c1.z);
        float pv7 = pf * q0[7] * __expf(-INV_EPS * c1.w);
        *(float4*)(prow + 4 * l)       = make_float4(pv0, pv1, pv2, pv3);
        *(float4*)(prow + 256 + 4 * l) = make_float4(pv4, pv5, pv6, pv7);
        csum = fmaf(pv0, c0.x, csum); csum = fmaf(pv1, c0.y, csum);
        csum = fmaf(pv2, c0.z, csum); csum = fmaf(pv3, c0.w, csum);
        csum = fmaf(pv4, c1.x, csum); csum = fmaf(pv5, c1.y, csum);
        csum = fmaf(pv6, c1.z, csum); csum = fmaf(pv7, c1.w, csum);
    }
#pragma unroll
    for (int off = 32; off; off >>= 1) csum += __shfl_xor(csum, off);
    if (l == 0) sPart[w] = csum;
    __syncthreads();
    if (tt == 0) {
        float tot = 0.0f;
#pragma unroll
        for (int ww = 0; ww < 8; ++ww) tot += sPart[ww];
        atomicAdd(&cost[b], tot);
    }
}

// ---------------------------------------------------------------------------
extern "C" void kernel_launch(void* const* d_in, const int* in_sizes, int n_in,
                              void* d_out, int out_size, void* d_ws, size_t ws_size,
                              hipStream_t stream) {
    const float* x = (const float*)d_in[0];
    const float* y = (const float*)d_in[1];
    float* out  = (float*)d_out;
    float* cost = out;                                   // [32]
    float* pi   = out + 32;                              // [32*512*512]
    float* C    = out + 32 + (size_t)NB * NN * NN;       // [32*512*512]

    float* ws = (float*)d_ws;
    float* nx = ws;                    // 16384
    float* ny = ws + 16384;            // 16384
    int* bars = (int*)(ws + 32768);    // padded barrier lines (BARS_N ints)

    // pi region reuse (33.55 MB):
    //   [xh: 8.4 MB][yh: 8.4 MB][Ef16: 16.8 MB]
    // xh/yh dead after gemm; cp double-buffer (1 MB) lives in xh region.
    // pi itself rewritten only at the very end (after the grid barrier).
    unsigned short* xh = (unsigned short*)pi;
    unsigned short* yh = xh + NELEM;
    __half* Ef = (__half*)(yh + NELEM);
    float* cp0 = pi;
    float* cp1 = pi + 256 * NN;

    norms_convert<<<dim3(8192), dim3(256), 0, stream>>>(
        x, y, nx, ny, xh, yh, cost, bars);
    gemm_cos_mfma<<<dim3(512), dim3(256), 0, stream>>>(
        xh, yh, nx, ny, C, Ef);

    const __half* Ef_p = Ef; const float* C_p = C;
    float* cp0_p = cp0; float* cp1_p = cp1;
    float* pi_p = pi; float* cost_p = cost; int* bars_p = bars;
    void* args[] = { &Ef_p, &C_p, &cp0_p, &cp1_p, &pi_p, &cost_p, &bars_p };
    hipLaunchCooperativeKernel(reinterpret_cast<void*>(sink_fused),
                               dim3(256), dim3(512), args, 0, stream);
}